// Round 11
// baseline (947.399 us; speedup 1.0000x reference)
//
#include <hip/hip_runtime.h>

typedef __attribute__((ext_vector_type(8))) short bf16x8;
typedef __attribute__((ext_vector_type(4))) float f32x4;

#define E_N   100000
#define ND_N  50000
#define NN_N  100000
#define SLOTS 32

__device__ __forceinline__ float b2f(unsigned short u) {
    return __uint_as_float(((unsigned int)u) << 16);
}
__device__ __forceinline__ unsigned short f2b(float f) {
    unsigned int b = __float_as_uint(f);
    b += 0x7fffu + ((b >> 16) & 1u);
    return (unsigned short)(b >> 16);
}
__device__ __forceinline__ float frcp(float x) { return __builtin_amdgcn_rcpf(x); }
__device__ __forceinline__ float fsig(float x) { return frcp(1.f + __expf(-x)); }
__device__ __forceinline__ float ftanhf(float x) {
    float e = __expf(2.f * x);
    return 1.f - 2.f * frcp(e + 1.f);
}

// async global->LDS, 16B per lane. LDS dest must be wave-uniform-base + lane*16.
#define GLDS16(g, l)                                                        \
    __builtin_amdgcn_global_load_lds(                                       \
        (const __attribute__((address_space(1))) void*)(g),                 \
        (__attribute__((address_space(3))) void*)(l), 16, 0, 0)

__device__ __forceinline__ void wait_and_barrier() {
    __builtin_amdgcn_sched_barrier(0);
    asm volatile("s_waitcnt vmcnt(0)" ::: "memory");
    __builtin_amdgcn_s_barrier();
    __builtin_amdgcn_sched_barrier(0);
}
__device__ __forceinline__ void plain_barrier() {
    __builtin_amdgcn_sched_barrier(0);
    __builtin_amdgcn_s_barrier();
    __builtin_amdgcn_sched_barrier(0);
}

// ---------------------------------------------------------------------------
__global__ void conv_f2b(const float* __restrict__ src, unsigned short* __restrict__ dst, int n4) {
    int i = blockIdx.x * 256 + threadIdx.x;
    if (i < n4) {
        float4 v = ((const float4*)src)[i];
        ushort4 o;
        o.x = f2b(v.x); o.y = f2b(v.y); o.z = f2b(v.z); o.w = f2b(v.w);
        ((ushort4*)dst)[i] = o;
    }
}

__global__ void zero_u4(uint4* __restrict__ p, int n4) {
    int i = blockIdx.x * 256 + threadIdx.x;
    if (i < n4) p[i] = make_uint4(0u, 0u, 0u, 0u);
}

// ---------------------------------------------------------------------------
// MFMA on one staged B buffer (192 rows x 64k, 24KB, XOR-swizzled) with
// register A fragments a[mi][kk]. r,z -> acc[0],acc[1]; third gate -> acc[G2].
template<int G2>
__device__ __forceinline__ void mma_tile(
    const unsigned char* __restrict__ lds_b, const bf16x8 a[2][2],
    f32x4 acc[4][2][2], int wn, int l15, int hi8)
{
    #pragma unroll
    for (int kk = 0; kk < 2; ++kk) {
        const int kb = kk * 64 + hi8 * 2;
        #pragma unroll
        for (int g = 0; g < 3; ++g) {
            const int gi = (g == 2) ? G2 : g;
            bf16x8 b[2];
            #pragma unroll
            for (int ni = 0; ni < 2; ++ni) {
                int brow = g * 64 + wn * 32 + ni * 16 + l15;
                b[ni] = *(const bf16x8*)(lds_b + brow * 128 + (kb ^ ((brow & 7) << 4)));
            }
            #pragma unroll
            for (int mi = 0; mi < 2; ++mi)
                #pragma unroll
                for (int ni = 0; ni < 2; ++ni)
                    acc[gi][mi][ni] = __builtin_amdgcn_mfma_f32_16x16x32_bf16(
                        a[mi][kk], b[ni], acc[gi][mi][ni], 0, 0, 0);
        }
    }
}

// ---------------------------------------------------------------------------
// GRU step. B (weights) double-buffered in LDS (2x24KB); A (h rows / gathered
// features) loaded DIRECTLY global->VGPR (blocked h layout makes the 16x16x32
// A-frag a full-line coalesced load), prefetched one k-tile ahead.
// Block: 512 thr (8 waves = 4M x 2N), tile = 128 edges x 64 cols x {r,z,n}.
__global__ __launch_bounds__(512, 4) void gru_step(
    const unsigned short* __restrict__ feat16,   // [NN, 64] bf16
    const int* __restrict__ emi,                 // [E, 3]
    const unsigned short* __restrict__ hprev,    // blocked [8][E][64] bf16 (t>0)
    unsigned short* __restrict__ hnext,          // blocked [8][E][64] bf16
    const unsigned short* __restrict__ wih,      // [1536, 64] bf16
    const unsigned short* __restrict__ whh,      // [1536, 512] bf16
    const float* __restrict__ bih,
    const float* __restrict__ bhh,
    int t)
{
    __shared__ __align__(16) unsigned char lds_mem[2 * 24576];   // 2 x B-tile

    const int tid = threadIdx.x;
    const int nwg = gridDim.x;
    const int logical = (blockIdx.x & 7) * (nwg >> 3) + (blockIdx.x >> 3);
    const int mb = (logical >> 3) * 128;
    const int nb = (logical & 7) * 64;
    const int hold_kt = nb >> 6;

    const int lane = tid & 63;
    const int wid  = tid >> 6;
    const int wm   = wid >> 1;
    const int wn   = wid & 1;
    const int l15  = lane & 15;
    const int hi8  = (lane >> 4) * 8;

    f32x4 acc[4][2][2];
    #pragma unroll
    for (int g = 0; g < 4; ++g)
        #pragma unroll
        for (int mi = 0; mi < 2; ++mi)
            #pragma unroll
            for (int ni = 0; ni < 2; ++ni) {
                f32x4 zz = {0.f, 0.f, 0.f, 0.f};
                acc[g][mi][ni] = zz;
            }

    // B staging coords: 1536 granules of 16B, 3 per thread
    int b_wr[3], b_sl2[3];
    #pragma unroll
    for (int q = 0; q < 3; ++q) {
        int c = tid + q * 512;
        int row = c >> 3;
        b_sl2[q] = (c & 7) ^ (row & 7);
        b_wr[q]  = (row >> 6) * 512 + nb + (row & 63);
    }

    // A-frag row indices for this wave (clamped)
    int ar[2];
    #pragma unroll
    for (int mi = 0; mi < 2; ++mi) {
        int r = mb + wm * 32 + mi * 16 + l15;
        ar[mi] = r < E_N ? r : E_N - 1;
    }

    // ---- prologue: stage W_ih -> buf0, W_hh k0 -> buf1; load x A-frags ----
    #pragma unroll
    for (int q = 0; q < 3; ++q)
        GLDS16(wih + (size_t)b_wr[q] * 64 + b_sl2[q] * 8, lds_mem + (tid + q * 512) * 16);
    if (t > 0) {
        #pragma unroll
        for (int q = 0; q < 3; ++q)
            GLDS16(whh + (size_t)b_wr[q] * 512 + b_sl2[q] * 8,
                   lds_mem + 24576 + (tid + q * 512) * 16);
    }

    bf16x8 ax[2][2];                       // x fragments [mi][kk]
    #pragma unroll
    for (int mi = 0; mi < 2; ++mi) {
        int node = emi[ar[mi] * 3 + t];
        const unsigned short* p = feat16 + (size_t)node * 64 + hi8;
        ax[mi][0] = *(const bf16x8*)p;
        ax[mi][1] = *(const bf16x8*)(p + 32);
    }

    bf16x8 areg[2][2][2];                  // h fragments [buf][mi][kk]
    if (t > 0) {
        #pragma unroll
        for (int mi = 0; mi < 2; ++mi) {
            const unsigned short* p = hprev + (size_t)ar[mi] * 64 + hi8;   // plane 0
            areg[0][mi][0] = *(const bf16x8*)p;
            areg[0][mi][1] = *(const bf16x8*)(p + 32);
        }
    }
    wait_and_barrier();

    // ---- x-phase: x @ W_ih^T (K = 64) from buf0 ----
    mma_tile<2>(lds_mem, ax, acc, wn, l15, hi8);
    plain_barrier();          // buf0 free for k-tile 1's stage

    unsigned int holdp[2][2][2] = {{{0u,0u},{0u,0u}},{{0u,0u},{0u,0u}}};

    // ---- h-phase: h @ W_hh^T, 8 plane-tiles; B ping-pong, A reg-prefetch ----
    if (t > 0) {
        #pragma unroll
        for (int kt = 0; kt < 8; ++kt) {
            unsigned char*       wr = lds_mem + (kt & 1) * 24576;
            const unsigned char* rd = lds_mem + ((kt & 1) ^ 1) * 24576;
            if (kt < 7) {
                const unsigned short* plane = hprev + (size_t)(kt + 1) * E_N * 64;
                #pragma unroll
                for (int mi = 0; mi < 2; ++mi) {
                    const unsigned short* p = plane + (size_t)ar[mi] * 64 + hi8;
                    areg[(kt + 1) & 1][mi][0] = *(const bf16x8*)p;
                    areg[(kt + 1) & 1][mi][1] = *(const bf16x8*)(p + 32);
                }
                const int k1 = (kt + 1) * 64;
                #pragma unroll
                for (int q = 0; q < 3; ++q)
                    GLDS16(whh + (size_t)b_wr[q] * 512 + k1 + b_sl2[q] * 8,
                           wr + (tid + q * 512) * 16);
            }
            if (kt == hold_kt) {
                // h_prev plane nb/64 is L2-hot (fetched last iter): capture hold
                const unsigned short* hp = hprev + (size_t)kt * E_N * 64;
                #pragma unroll
                for (int ni = 0; ni < 2; ++ni)
                    #pragma unroll
                    for (int mi = 0; mi < 2; ++mi)
                        #pragma unroll
                        for (int jp = 0; jp < 2; ++jp) {
                            int r0 = mb + wm * 32 + mi * 16 + (lane >> 4) * 4 + jp * 2;
                            int r1 = r0 + 1;
                            r0 = r0 < E_N ? r0 : E_N - 1;
                            r1 = r1 < E_N ? r1 : E_N - 1;
                            int c = wn * 32 + ni * 16 + l15;
                            unsigned int lo = hp[(size_t)r0 * 64 + c];
                            unsigned int hi = hp[(size_t)r1 * 64 + c];
                            holdp[ni][mi][jp] = lo | (hi << 16);
                        }
            }
            mma_tile<3>(rd, areg[kt & 1], acc, wn, l15, hi8);
            wait_and_barrier();
        }
    }

    // ---- epilogue: gate math -> LDS out tile (buf0) -> coalesced blocked store ----
    unsigned char* lout = lds_mem;
    #pragma unroll
    for (int ni = 0; ni < 2; ++ni) {
        const int col = nb + wn * 32 + ni * 16 + l15;
        const float br0  = bih[col] + bhh[col];
        const float bz0  = bih[512 + col] + bhh[512 + col];
        const float bin_ = bih[1024 + col];
        const float bhn_ = bhh[1024 + col];
        #pragma unroll
        for (int mi = 0; mi < 2; ++mi) {
            #pragma unroll
            for (int j = 0; j < 4; ++j) {
                float r = fsig(acc[0][mi][ni][j] + br0);
                float z = fsig(acc[1][mi][ni][j] + bz0);
                float n = ftanhf(acc[2][mi][ni][j] + bin_ + r * (acc[3][mi][ni][j] + bhn_));
                float hold = (t > 0)
                    ? b2f((unsigned short)((holdp[ni][mi][j >> 1] >> ((j & 1) * 16)) & 0xffffu))
                    : 0.f;
                float hv = (1.f - z) * n + z * hold;
                int row = wm * 32 + mi * 16 + (lane >> 4) * 4 + j;
                int oc  = (wn * 32 + ni * 16 + l15) * 2;
                *(unsigned short*)(lout + row * 128 + (oc ^ ((row & 7) << 4))) = f2b(hv);
            }
        }
    }
    __syncthreads();
    const size_t oplane = (size_t)(nb >> 6) * E_N * 64;
    #pragma unroll
    for (int q = 0; q < 2; ++q) {
        int chunk = tid + q * 512;
        int row = chunk >> 3, c8 = chunk & 7;
        int grow = mb + row;
        if (grow < E_N) {
            uint4 v = *(const uint4*)(lout + row * 128 + ((c8 * 16) ^ ((row & 7) << 4)));
            *(uint4*)(hnext + oplane + (size_t)grow * 64 + c8 * 8) = v;
        }
    }
}

// ---------------------------------------------------------------------------
// attention logits + leaky relu. One wave per edge; 8-lane groups own a head.
// hl is blocked [8][E][64]; head h == plane h (64 cols each).
__global__ __launch_bounds__(256) void attn_logits(
    const unsigned short* __restrict__ hl, const float* __restrict__ attnw,
    float* __restrict__ a)
{
    int e = blockIdx.x * 4 + (threadIdx.x >> 6);
    int lane = threadIdx.x & 63;
    int h = lane >> 3;
    int c8 = lane & 7;
    uint4 v = *(const uint4*)(hl + (size_t)h * E_N * 64 + (size_t)e * 64 + c8 * 8);
    int dp = c8 * 8;
    float4 w0 = *(const float4*)(attnw + h * 64 + dp);
    float4 w1 = *(const float4*)(attnw + h * 64 + dp + 4);
    const unsigned short* u = (const unsigned short*)&v;
    float s = b2f(u[0]) * w0.x + b2f(u[1]) * w0.y + b2f(u[2]) * w0.z + b2f(u[3]) * w0.w
            + b2f(u[4]) * w1.x + b2f(u[5]) * w1.y + b2f(u[6]) * w1.z + b2f(u[7]) * w1.w;
    s += __shfl_xor(s, 1);
    s += __shfl_xor(s, 2);
    s += __shfl_xor(s, 4);
    if ((lane & 7) == 0)
        a[e * 8 + h] = s > 0.f ? s : 0.01f * s;
}

// per-dst edge lists (order within a list is arbitrary)
__global__ __launch_bounds__(256) void build_lists(
    const int* __restrict__ dstp, int* __restrict__ cnt, int* __restrict__ lists)
{
    int e = blockIdx.x * 256 + threadIdx.x;
    if (e < E_N) {
        int d = dstp[e];
        int slot = atomicAdd(&cnt[d], 1);
        if (slot < SLOTS) lists[(size_t)d * SLOTS + slot] = e;
    }
}

// One wave per dst: segment softmax + weighted gather-sum, plain stores.
// hl blocked [8][E][64]; lane's 8 cols sit in plane h = lane>>3.
__global__ __launch_bounds__(256) void aggregate(
    const unsigned short* __restrict__ hl, const float* __restrict__ a,
    const int* __restrict__ lists, const int* __restrict__ cnt,
    float* __restrict__ out)
{
    int d = blockIdx.x * 4 + (threadIdx.x >> 6);
    int lane = threadIdx.x & 63;
    int n = cnt[d];
    n = n < SLOTS ? n : SLOTS;
    const int h = lane >> 3;
    const int c8 = lane & 7;
    const int* lst = lists + (size_t)d * SLOTS;
    const unsigned short* plane = hl + (size_t)h * E_N * 64;

    float m = -1e30f;
    for (int i = 0; i < n; ++i)
        m = fmaxf(m, a[lst[i] * 8 + h]);
    float s = 0.f;
    for (int i = 0; i < n; ++i)
        s += __expf(a[lst[i] * 8 + h] - m);
    float rs = frcp(s);

    float acc[8] = {0.f, 0.f, 0.f, 0.f, 0.f, 0.f, 0.f, 0.f};
    for (int i = 0; i < n; ++i) {
        int e = lst[i];
        float alpha = __expf(a[e * 8 + h] - m) * rs;
        uint4 v = *(const uint4*)(plane + (size_t)e * 64 + c8 * 8);
        const unsigned short* u = (const unsigned short*)&v;
        #pragma unroll
        for (int j = 0; j < 8; ++j)
            acc[j] += alpha * b2f(u[j]);
    }
    float4 o0 = {acc[0], acc[1], acc[2], acc[3]};
    float4 o1 = {acc[4], acc[5], acc[6], acc[7]};
    float* op = out + (size_t)d * 512 + lane * 8;
    *(float4*)op = o0;
    *(float4*)(op + 4) = o1;
}

// ---------------------------------------------------------------------------
extern "C" void kernel_launch(void* const* d_in, const int* in_sizes, int n_in,
                              void* d_out, int out_size, void* d_ws, size_t ws_size,
                              hipStream_t stream)
{
    const float* features = (const float*)d_in[0];
    const float* W_ih     = (const float*)d_in[1];
    const float* W_hh     = (const float*)d_in[2];
    const float* b_ih     = (const float*)d_in[3];
    const float* b_hh     = (const float*)d_in[4];
    const float* attnw    = (const float*)d_in[5];
    const int*   emi      = (const int*)d_in[6];
    const int*   dstp     = (const int*)d_in[7];

    char* ws = (char*)d_ws;
    size_t off = 0;
    auto alloc = [&](size_t bytes) -> void* {
        void* p = ws + off;
        off = (off + bytes + 255) & ~(size_t)255;
        return p;
    };
    unsigned short* feat16 = (unsigned short*)alloc((size_t)NN_N * 64 * 2);
    unsigned short* wih16  = (unsigned short*)alloc((size_t)1536 * 64 * 2);
    unsigned short* whh16  = (unsigned short*)alloc((size_t)1536 * 512 * 2);
    unsigned short* h0     = (unsigned short*)alloc((size_t)E_N * 512 * 2);   // blocked [8][E][64]
    unsigned short* h1     = (unsigned short*)alloc((size_t)E_N * 512 * 2);   // blocked [8][E][64]
    float*          abuf   = (float*)alloc((size_t)E_N * 8 * 4);
    int*            cnt    = (int*)alloc((size_t)ND_N * 4);
    int*            lists  = (int*)alloc((size_t)ND_N * SLOTS * 4);

    conv_f2b<<<(NN_N * 64 / 4 + 255) / 256, 256, 0, stream>>>(features, feat16, NN_N * 64 / 4);
    conv_f2b<<<(1536 * 64 / 4 + 255) / 256, 256, 0, stream>>>(W_ih, wih16, 1536 * 64 / 4);
    conv_f2b<<<(1536 * 512 / 4 + 255) / 256, 256, 0, stream>>>(W_hh, whh16, 1536 * 512 / 4);

    zero_u4<<<(ND_N / 4 + 255) / 256, 256, 0, stream>>>((uint4*)cnt, ND_N / 4);

    // GRU: 3 steps; grid = 782 m-tiles x 8 n-tiles = 6256 (divisible by 8)
    const int grid = ((E_N + 127) / 128) * 8;
    gru_step<<<grid, 512, 0, stream>>>(feat16, emi, nullptr, h0, wih16, whh16, b_ih, b_hh, 0);
    gru_step<<<grid, 512, 0, stream>>>(feat16, emi, h0, h1, wih16, whh16, b_ih, b_hh, 1);
    gru_step<<<grid, 512, 0, stream>>>(feat16, emi, h1, h0, wih16, whh16, b_ih, b_hh, 2);

    // attention + dst-gather softmax/aggregation (no output atomics)
    attn_logits<<<E_N / 4, 256, 0, stream>>>(h0, attnw, abuf);
    build_lists<<<(E_N + 255) / 256, 256, 0, stream>>>(dstp, cnt, lists);
    aggregate<<<ND_N / 4, 256, 0, stream>>>(h0, abuf, lists, cnt, (float*)d_out);
}